// Round 1
// baseline (85.613 us; speedup 1.0000x reference)
//
#include <hip/hip_runtime.h>

#define ROWS_PER_BLOCK 256
#define D 16
#define OUTD 153  // 1 + 16 + 16 + 120

__global__ __launch_bounds__(256) void taylor_fm_kernel(const float* __restrict__ x,
                                                        float* __restrict__ out,
                                                        int nrows) {
    __shared__ float xs[ROWS_PER_BLOCK * D];       // 16 KiB staged input rows
    __shared__ unsigned char tab[120];             // triu (i,j) packed as (i<<4)|j
    const int tid = threadIdx.x;
    const int r0 = blockIdx.x * ROWS_PER_BLOCK;

    // Build the upper-triangle index table once per block (matches np.triu_indices(16, k=1))
    if (tid < 120) {
        int rem = tid, i = 0;
        while (rem >= 15 - i) { rem -= 15 - i; ++i; }
        tab[tid] = (unsigned char)((i << 4) | (i + 1 + rem));
    }

    // Stage input rows: fully coalesced float4 loads
    const int nrow_blk = min(ROWS_PER_BLOCK, nrows - r0);
    const float4* src = reinterpret_cast<const float4*>(x + (size_t)r0 * D);
    float4* dst = reinterpret_cast<float4*>(xs);
    const int nf4 = nrow_blk * D / 4;              // D=16 -> always multiple of 4
    for (int i = tid; i < nf4; i += ROWS_PER_BLOCK) dst[i] = src[i];
    __syncthreads();

    const float inv_rrd = 0.5f;                    // 1 / 16^0.25
    const float s_diag  = 0.17677669529663687f;    // 1 / (4*sqrt(2))
    const float s_tri   = 0.25f;                   // 1 / 4

    float* outb = out + (size_t)r0 * OUTD;
    const int total = nrow_blk * OUTD;

    // flat output index o = tid + k*256; track (row, col) incrementally (no div)
    int row = (tid >= OUTD) ? 1 : 0;
    int col = tid - row * OUTD;
    for (int o = tid; o < total; o += ROWS_PER_BLOCK) {
        const float* xr = xs + row * D;
        float v;
        if (col == 0) {
            v = 1.0f;
        } else if (col < 17) {
            v = xr[col - 1] * inv_rrd;
        } else if (col < 33) {
            float a = xr[col - 17];
            v = a * a * s_diag;
        } else {
            int p = tab[col - 33];
            v = xr[p >> 4] * xr[p & 15] * s_tri;
        }
        outb[o] = v;                               // consecutive lanes -> consecutive dwords
        // advance by 256 = 153 + 103
        col += ROWS_PER_BLOCK - OUTD; row += 1;
        if (col >= OUTD) { col -= OUTD; row += 1; }
    }
}

extern "C" void kernel_launch(void* const* d_in, const int* in_sizes, int n_in,
                              void* d_out, int out_size, void* d_ws, size_t ws_size,
                              hipStream_t stream) {
    const float* x = (const float*)d_in[0];
    float* out = (float*)d_out;
    const int nrows = in_sizes[0] / D;             // 4*16*8192 = 524288
    const int blocks = (nrows + ROWS_PER_BLOCK - 1) / ROWS_PER_BLOCK;
    taylor_fm_kernel<<<blocks, ROWS_PER_BLOCK, 0, stream>>>(x, out, nrows);
}

// Round 2
// 72.312 us; speedup vs baseline: 1.1839x; 1.1839x over previous
//
#include <hip/hip_runtime.h>

#define D 16
#define OUTD 153                 // 1 + 16 + 16 + 120
#define ROWS_PER_BLOCK 64
#define THREADS 256

// Emit columns [LO, HI) of one output row into dst (LDS), fully unrolled.
// All indices/scales fold to compile-time constants; xv[] stays in registers.
template<int LO, int HI>
__device__ __forceinline__ void emit_cols(const float xv[D], float* dst) {
    if (LO <= 0 && 0 < HI) dst[0] = 1.0f;
#pragma unroll
    for (int k = 0; k < D; ++k) {
        const int c1 = 1 + k;                    // linear segment: x / 16^0.25
        if (c1 >= LO && c1 < HI) dst[c1] = xv[k] * 0.5f;
        const int c2 = 17 + k;                   // diagonal: x^2 / (4*sqrt(2))
        if (c2 >= LO && c2 < HI) dst[c2] = xv[k] * xv[k] * 0.17677669529663687f;
    }
#pragma unroll
    for (int i = 0; i < D; ++i) {
#pragma unroll
        for (int j = i + 1; j < D; ++j) {        // upper triangle: x_i*x_j / 4
            const int c = 33 + (15 * i - (i * (i - 1)) / 2) + (j - i - 1);
            if (c >= LO && c < HI) dst[c] = xv[i] * xv[j] * 0.25f;
        }
    }
}

__global__ __launch_bounds__(THREADS) void taylor_fm_kernel(const float* __restrict__ x,
                                                            float* __restrict__ out,
                                                            int nrows) {
    __shared__ float olds[ROWS_PER_BLOCK * OUTD];   // 38.25 KiB, flat global order
    const int tid = threadIdx.x;
    const int q   = tid >> 6;                        // wave id (uniform per wave)
    const int r   = tid & 63;                        // row within block
    const int r0  = blockIdx.x * ROWS_PER_BLOCK;
    const int row = r0 + r;

    if (row < nrows) {
        // Row's 16 x-values into registers (4 waves share rows -> L1 hits)
        const float4* xrow = reinterpret_cast<const float4*>(x + (size_t)row * D);
        float xv[D];
#pragma unroll
        for (int m = 0; m < 4; ++m) {
            float4 v = xrow[m];
            xv[4 * m + 0] = v.x; xv[4 * m + 1] = v.y;
            xv[4 * m + 2] = v.z; xv[4 * m + 3] = v.w;
        }
        float* dst = olds + r * OUTD;                // lane stride 153 (odd) -> no bank conflict
        if      (q == 0) emit_cols<0,   39 >(xv, dst);
        else if (q == 1) emit_cols<39,  77 >(xv, dst);
        else if (q == 2) emit_cols<77,  115>(xv, dst);
        else             emit_cols<115, 153>(xv, dst);
    }
    __syncthreads();

    // Stream the block's output chunk: flat, fully coalesced float4 stores.
    const int nrow_blk = min(ROWS_PER_BLOCK, nrows - r0);
    const int nelem = nrow_blk * OUTD;
    const int nf4 = nelem >> 2;
    float4* gout = reinterpret_cast<float4*>(out + (size_t)r0 * OUTD);  // 39168*bid bytes, 16B-aligned
    const float4* lsrc = reinterpret_cast<const float4*>(olds);
    for (int g = tid; g < nf4; g += THREADS) gout[g] = lsrc[g];
    const int rem = nelem & 3;                       // generic tail (absent for 64-row blocks)
    if (tid < rem) out[(size_t)r0 * OUTD + nf4 * 4 + tid] = olds[nf4 * 4 + tid];
}

extern "C" void kernel_launch(void* const* d_in, const int* in_sizes, int n_in,
                              void* d_out, int out_size, void* d_ws, size_t ws_size,
                              hipStream_t stream) {
    const float* x = (const float*)d_in[0];
    float* out = (float*)d_out;
    const int nrows = in_sizes[0] / D;               // 4*16*8192 = 524288
    const int blocks = (nrows + ROWS_PER_BLOCK - 1) / ROWS_PER_BLOCK;
    taylor_fm_kernel<<<blocks, THREADS, 0, stream>>>(x, out, nrows);
}